// Round 5
// baseline (7078.854 us; speedup 1.0000x reference)
//
#include <hip/hip_runtime.h>
#include <hip/hip_bf16.h>

// Problem constants (fixed by the reference)
#define BATCH 8
#define NPTS  4096      // N
#define CCH   128      // C
#define KNN_K 16       // K

// KNN spatial grid
#define GD  32                  // cells per dim
#define GC  (GD * GD * GD)      // 32768 cells per batch
#define GLO (-4.6f)             // fixed domain [-4.6, 4.6); N(0,1) outliers clamp
#define GH  (9.2f / 32.0f)      // cell size 0.2875
#define GIH (32.0f / 9.2f)

typedef __attribute__((ext_vector_type(8))) short  bf16x8;  // 8 bf16 = 4 VGPRs
typedef __attribute__((ext_vector_type(4))) float  f32x4;   // MFMA acc

// ---------------------------------------------------------------------------
// ws layout (bytes):
//   [0)          xTb   : B*N*C bf16      = 8,388,608
//   [8388608)    Wb    : C*C  bf16       =    32,768
//   [8421376)    scale : C fp32          =       512
//   [8421888)    bias  : C fp32          =       512
//   [8422400)    pts   : B*N float4(x,y,z,s) = 524,288
//   [8946688)    knn   : B*N*K u16       = 1,048,576
//   [9995264)    Zb    : B*N*C bf16      = 8,388,608   (Z = W@x, [B,N,C])
// Grid scratch OVERLAYS Zb (zgemm writes Zb only after knn completes):
//   Zb+0         counts : u32[8*GC]      = 1,048,576
//   Zb+1048576   fill   : u32[8*GC]      = 1,048,576
//   Zb+2097152   starts : u32[8*GC]      = 1,048,576
//   Zb+3145728   cellid : u32[B*N]       =   131,072
//   Zb+3276800   psort  : float4[B*N]    =   524,288
//   Zb+3801088   isort  : u16[B*N]       =    65,536   (ends 3,866,624 < 8 MB)
// ---------------------------------------------------------------------------

static __device__ __forceinline__ short f2bf(float v) {
    __hip_bfloat16 h = __float2bfloat16(v);   // RNE
    return __builtin_bit_cast(short, h);
}

// LDS-tiled transpose: x [B,C,N] fp32 -> xTb [B,N,C] bf16.
__global__ __launch_bounds__(256) void transpose_kernel(
    const float* __restrict__ x, short* __restrict__ xTb)
{
    __shared__ short tile[64 * 66];
    const int tid = threadIdx.x;
    const int b   = blockIdx.x >> 7;         // 8 batches
    const int rem = blockIdx.x & 127;
    const int nt  = rem >> 1;                // 64 n-tiles of 64
    const int ct  = rem & 1;                 // 2 c-tiles of 64

    #pragma unroll
    for (int it = 0; it < 16; ++it) {
        const int idx = it * 256 + tid;
        const int cc  = idx >> 6;
        const int nn  = idx & 63;
        const float v = x[(size_t)(b * CCH + ct * 64 + cc) * NPTS + nt * 64 + nn];
        tile[cc * 66 + nn] = f2bf(v);
    }
    __syncthreads();
    #pragma unroll
    for (int it = 0; it < 16; ++it) {
        const int idx = it * 256 + tid;
        const int nn  = idx >> 6;
        const int cc  = idx & 63;
        xTb[(size_t)(b * NPTS + nt * 64 + nn) * CCH + ct * 64 + cc] = tile[cc * 66 + nn];
    }
}

// Small prep: W -> bf16; fold BN affine; xyz -> SoA float4 with |p|^2
__global__ __launch_bounds__(256) void small_prep_kernel(
    const float* __restrict__ xyz, const float* __restrict__ W,
    const float* __restrict__ gamma, const float* __restrict__ beta,
    const float* __restrict__ rmean, const float* __restrict__ rvar,
    short* __restrict__ Wb, float* __restrict__ scale, float* __restrict__ bias,
    float4* __restrict__ pts)
{
    const int t = blockIdx.x * 256 + threadIdx.x;   // grid covers B*N = 32768
    if (t < CCH * CCH) Wb[t] = f2bf(W[t]);
    if (t < CCH) {
        const float s = gamma[t] / sqrtf(rvar[t] + 1e-5f);
        scale[t] = s;
        bias[t]  = beta[t] - rmean[t] * s;
    }
    {
        #pragma clang fp contract(off)
        const float px = xyz[3 * t + 0];
        const float py = xyz[3 * t + 1];
        const float pz = xyz[3 * t + 2];
        const float s  = px * px + py * py + pz * pz;   // matches ref s = sum(xyz*xyz)
        pts[t] = make_float4(px, py, pz, s);
    }
}

// ---- grid build ----------------------------------------------------------

__global__ __launch_bounds__(256) void zero_kernel(uint4* __restrict__ p)
{
    p[blockIdx.x * 256 + threadIdx.x] = make_uint4(0, 0, 0, 0);  // 2 MB: counts+fill
}

static __device__ __forceinline__ int cell_of(float v) {
    int c = (int)floorf((v - GLO) * GIH);
    return c < 0 ? 0 : (c > GD - 1 ? GD - 1 : c);
}

__global__ __launch_bounds__(256) void hist_kernel(
    const float4* __restrict__ pts, unsigned* __restrict__ counts,
    unsigned* __restrict__ cellid)
{
    const int t = blockIdx.x * 256 + threadIdx.x;   // B*N
    const float4 p = pts[t];
    const int cell = (cell_of(p.z) * GD + cell_of(p.y)) * GD + cell_of(p.x);
    cellid[t] = (unsigned)cell;
    atomicAdd(&counts[((t >> 12) << 15) + cell], 1u);
}

// exclusive scan of 32768 cell counts per batch; one block per batch
__global__ __launch_bounds__(1024) void scan_kernel(
    const unsigned* __restrict__ counts, unsigned* __restrict__ starts)
{
    __shared__ unsigned part[1024];
    const int b = blockIdx.x, t = threadIdx.x;
    const int base = (b << 15) + t * 32;
    unsigned sum = 0;
    #pragma unroll 4
    for (int k = 0; k < 32; ++k) sum += counts[base + k];
    part[t] = sum;
    __syncthreads();
    for (int off = 1; off < 1024; off <<= 1) {
        const unsigned v = (t >= off) ? part[t - off] : 0u;
        __syncthreads();
        part[t] += v;
        __syncthreads();
    }
    unsigned run = (t == 0) ? 0u : part[t - 1];
    #pragma unroll 4
    for (int k = 0; k < 32; ++k) {
        starts[base + k] = run;
        run += counts[base + k];
    }
}

__global__ __launch_bounds__(256) void scatter_kernel(
    const float4* __restrict__ pts, const unsigned* __restrict__ cellid,
    const unsigned* __restrict__ starts, unsigned* __restrict__ fill,
    float4* __restrict__ psort, unsigned short* __restrict__ isort)
{
    const int t = blockIdx.x * 256 + threadIdx.x;   // B*N
    const unsigned idx = ((unsigned)(t >> 12) << 15) + cellid[t];
    const unsigned pos = starts[idx] + atomicAdd(&fill[idx], 1u);
    const int d = ((t >> 12) << 12) + (int)pos;
    psort[d] = pts[t];
    isort[d] = (unsigned short)(t & 4095);
}

// ---- grid KNN ------------------------------------------------------------

#define PK_(h, l) ((((unsigned long long)(h)) << 32) | (unsigned long long)(l))

// KNN v5: spatial-grid candidate pruning + buffered top-k with bitonic flush.
// 4 queries per wave (consecutive in CELL-SORTED order -> shared home cell),
// lane = g*16+s. Expanding Chebyshev rings around the home cell; ring r is
// skipped (and the query retired) once dmin(q, exterior of B_{r-1})^2 > tau.
// Keys are (mono(d2), orig_j) -> selection is processing-order-independent;
// filter is d2 <= tau (strict < relied on ascending-j order, no longer true).
// Termination uses a 1e-4 distance slack to absorb cell-boundary fp rounding.
// d2 expression is bit-identical to the reference (contract off, same order,
// coordinates copied bitwise through psort).
__global__ __launch_bounds__(256) void knn_grid_kernel(
    const float4* __restrict__ psort, const unsigned short* __restrict__ isort,
    const unsigned* __restrict__ starts, const unsigned* __restrict__ counts,
    unsigned short* __restrict__ knn)
{
    const int lane = threadIdx.x & 63;
    const int wid  = threadIdx.x >> 6;
    const int g    = lane >> 4;                 // group (query) 0..3
    const int s    = lane & 15;                 // slot within group
    const int wq   = blockIdx.x * 16 + wid * 4; // first sorted query of wave
    const int b    = wq >> 12;
    const int sp   = (wq & 4095) + g;           // this lane's sorted position
    const float4*         ps  = psort + (b << 12);
    const unsigned short* is  = isort + (b << 12);
    const unsigned*       cst = starts + (b << 15);
    const unsigned*       ccn = counts + (b << 15);

    const float4 q  = ps[sp];                   // group-uniform
    const int    qi = (int)is[sp];              // orig within-batch index

    // home cell = cell of the wave's first query (wave-uniform)
    int hx = cell_of(q.x), hy = cell_of(q.y), hz = cell_of(q.z);
    hx = __shfl(hx, 0); hy = __shfl(hy, 0); hz = __shfl(hz, 0);
    const float hlx = GLO + hx * GH;            // home box lo per dim
    const float hly = GLO + hy * GH;
    const float hlz = GLO + hz * GH;

    const unsigned SENT_HI = 0xFF7FFFFFu;       // mono(+3.4e38)
    const unsigned SENT_LO = 0xFFFFFFFFu;

    unsigned lhi = SENT_HI, llo = SENT_LO;      // sorted top-16 list (asc)
    float bufD = 0.f;                           // survivor buffer (slot s)
    int   bufJ = 0;
    int   cnt  = 0;                             // valid entries (group-uniform)
    float tau  = 3.4e38f;
    const int      gsh   = g << 4;
    const unsigned smask = (1u << s) - 1u;

    auto sort16 = [&](unsigned& hi, unsigned& lo) {
        #define CE_(K, J, OFF) { \
            const unsigned ohi = (unsigned)__builtin_amdgcn_ds_swizzle((int)hi, OFF); \
            const unsigned olo = (unsigned)__builtin_amdgcn_ds_swizzle((int)lo, OFF); \
            const bool olt = PK_(ohi, olo) < PK_(hi, lo); \
            const bool sel = (((s & (J)) == 0) == ((s & (K)) == 0)); \
            const bool tk  = sel ? olt : !olt; \
            hi = tk ? ohi : hi; lo = tk ? olo : lo; }
        CE_(2, 1, 0x041F)
        CE_(4, 2, 0x081F)  CE_(4, 1, 0x041F)
        CE_(8, 4, 0x101F)  CE_(8, 2, 0x081F)  CE_(8, 1, 0x041F)
        CE_(16, 8, 0x201F) CE_(16, 4, 0x101F) CE_(16, 2, 0x081F) CE_(16, 1, 0x041F)
        #undef CE_
    };

    auto refresh_tau = [&]() {
        const unsigned thi = (unsigned)__builtin_amdgcn_ds_swizzle((int)lhi, 0x01F0);
        tau = __uint_as_float((thi & 0x80000000u) ? (thi & 0x7FFFFFFFu) : ~thi);
    };

    auto flush = [&]() {
        const unsigned u = __float_as_uint(bufD);
        unsigned khi = (u & 0x80000000u) ? ~u : (u | 0x80000000u);
        unsigned klo = (unsigned)bufJ;
        const bool inval = (s >= cnt);
        khi = inval ? SENT_HI : khi;
        klo = inval ? SENT_LO : klo;
        sort16(khi, klo);
        {
            const unsigned rhi = (unsigned)__builtin_amdgcn_ds_swizzle((int)khi, 0x3C1F);
            const unsigned rlo = (unsigned)__builtin_amdgcn_ds_swizzle((int)klo, 0x3C1F);
            const bool rlt = PK_(rhi, rlo) < PK_(lhi, llo);
            lhi = rlt ? rhi : lhi; llo = rlt ? rlo : llo;
        }
        #define MC_(J, OFF) { \
            const unsigned ohi = (unsigned)__builtin_amdgcn_ds_swizzle((int)lhi, OFF); \
            const unsigned olo = (unsigned)__builtin_amdgcn_ds_swizzle((int)llo, OFF); \
            const bool olt = PK_(ohi, olo) < PK_(lhi, llo); \
            const bool tk  = ((s & (J)) == 0) ? olt : !olt; \
            lhi = tk ? ohi : lhi; llo = tk ? olo : llo; }
        MC_(8, 0x201F) MC_(4, 0x101F) MC_(2, 0x081F) MC_(1, 0x041F)
        #undef MC_
        refresh_tau();
        cnt = 0;
    };

    auto append = [&](float d2v, int jov) {
        const unsigned long long mask = __ballot(d2v <= tau);
        if (mask) {
            const unsigned sub = (unsigned)((mask >> gsh) & 0xFFFFull);
            const int m = __popc(sub);
            if (__any(cnt + m > 15)) flush();
            const bool surv = (sub >> s) & 1u;
            const int rank  = __popc(sub & smask);
            const int dest  = surv ? (cnt + rank) : 15;   // slot 15 free when m<16
            const int addr  = (gsh | dest) << 2;
            const int nd = __builtin_amdgcn_ds_permute(addr, __float_as_int(d2v));
            const int nj = __builtin_amdgcn_ds_permute(addr, jov);
            const bool got = (s >= cnt) & (s < cnt + m);
            bufD = got ? __int_as_float(nd) : bufD;
            bufJ = got ? nj : bufJ;
            cnt += m;
        }
    };

    for (int r = 0; r < GD; ++r) {
        if (r >= 1) {
            // exact lower bound on distance to any unprocessed cell (ring>=r):
            // distance from q to exterior of B_{r-1} (home box dilated r-1 cells)
            const float e  = (float)(r - 1) * GH;
            const float m1 = fminf(q.x - (hlx - e), (hlx + GH + e) - q.x);
            const float m2 = fminf(q.y - (hly - e), (hly + GH + e) - q.y);
            const float m3 = fminf(q.z - (hlz - e), (hlz + GH + e) - q.z);
            const float dm = fmaxf(fminf(m1, fminf(m2, m3)) - 1e-4f, 0.f);
            if (__all(dm * dm > tau)) break;
        }
        for (int dz = -r; dz <= r; ++dz) {
            const int zz = hz + dz;
            if ((unsigned)zz >= GD) continue;
            const int adz = dz < 0 ? -dz : dz;
            for (int dy = -r; dy <= r; ++dy) {
                const int yy = hy + dy;
                if ((unsigned)yy >= GD) continue;
                const int ady  = dy < 0 ? -dy : dy;
                const bool face = ((adz > ady ? adz : ady) == r);
                const int step = (face || r == 0) ? 1 : 2 * r;
                for (int dx = -r; dx <= r; dx += step) {
                    const int xx = hx + dx;
                    if ((unsigned)xx >= GD) continue;
                    const int ci = (zz * GD + yy) * GD + xx;
                    const unsigned st = cst[ci];
                    const unsigned cn = ccn[ci];
                    for (unsigned c0 = 0; c0 < cn; c0 += 16) {
                        const bool val = (c0 + (unsigned)s) < cn;
                        float d2 = __builtin_inff();
                        int   jo = 0;
                        if (val) {
                            const float4 p = ps[st + c0 + s];
                            jo = (int)is[st + c0 + s];
                            {
                                #pragma clang fp contract(off)
                                d2 = (q.w + p.w) - 2.0f * (q.x * p.x + q.y * p.y + q.z * p.z);
                            }
                        }
                        append(d2, jo);
                    }
                }
            }
        }
        if (__any(cnt != 0)) flush();           // tighten tau for termination
    }
    if (__any(cnt != 0)) flush();               // safety drain

    unsigned short* o = knn + ((((size_t)b << 12) + qi) << 4);
    o[s] = (unsigned short)llo;                 // j of s-th smallest (d2, j)
}

// Dense GEMM: Z[g, c] = sum_k xTb[g, k] * W[c, k], Z bf16 [B*N, C].
// Wave = 16 rows x 128 cols; verified fragment mappings (A: m=lane&15,
// k=(lane>>4)*8+j; B: n=lane&15, same k-slice; C/D: col=lane&15,
// row=(lane>>4)*4+reg). W staged in LDS, pitch 136.
__global__ __launch_bounds__(256) void zgemm_kernel(
    const short* __restrict__ xTb, const short* __restrict__ Wb,
    short* __restrict__ Zb)
{
    __shared__ short sW[CCH * 136];
    const int lane = threadIdx.x & 63;
    const int wid  = threadIdx.x >> 6;
    const int kl   = lane & 15;
    const int q8   = (lane >> 4) * 8;

    #pragma unroll
    for (int it = 0; it < 8; ++it) {             // stage W: 16384 elems
        const int e = (it * 256 + threadIdx.x) * 8;
        const int r = e >> 7, c = e & 127;
        *(bf16x8*)(sW + r * 136 + c) = *(const bf16x8*)(Wb + e);
    }

    const int    G    = blockIdx.x * 64 + wid * 16 + kl;   // A-row (flat B*N)
    const size_t arow = (size_t)G * CCH;
    __syncthreads();

    const f32x4 zero = {0.f, 0.f, 0.f, 0.f};
    f32x4 acc[8];
    #pragma unroll
    for (int t = 0; t < 8; ++t) acc[t] = zero;

    #pragma unroll
    for (int kk = 0; kk < 4; ++kk) {
        const bf16x8 a = *(const bf16x8*)(xTb + arow + kk * 32 + q8);
        #pragma unroll
        for (int t = 0; t < 8; ++t) {
            const bf16x8 bf = *(const bf16x8*)(sW + (t * 16 + kl) * 136 + kk * 32 + q8);
            acc[t] = __builtin_amdgcn_mfma_f32_16x16x32_bf16(a, bf, acc[t], 0, 0, 0);
        }
    }

    const int rbase = blockIdx.x * 64 + wid * 16 + (lane >> 4) * 4;
    #pragma unroll
    for (int t = 0; t < 8; ++t)
        #pragma unroll
        for (int r = 0; r < 4; ++r)
            Zb[(size_t)(rbase + r) * CCH + t * 16 + kl] = f2bf(acc[t][r]);
}

// Gather + BN + ReLU + max-over-16, then coalesced store via LDS transpose.
__global__ __launch_bounds__(256) void gmax_kernel(
    const short* __restrict__ Zb, const unsigned short* __restrict__ knn,
    const float* __restrict__ scale, const float* __restrict__ bias,
    float* __restrict__ out)
{
    __shared__ float sm[16][132];
    const int lane = threadIdx.x & 63;
    const int wid  = threadIdx.x >> 6;
    const int n0   = blockIdx.x * 16;           // flat point base (B*N)
    const int b    = blockIdx.x >> 8;           // 256 blocks per batch
    const float s0 = scale[2 * lane],   s1 = scale[2 * lane + 1];
    const float t0 = bias[2 * lane],    t1 = bias[2 * lane + 1];

    for (int p = 0; p < 4; ++p) {
        const int n = n0 + wid * 4 + p;         // flat
        const unsigned short* kr = knn + (size_t)n * 16;
        float m0 = 0.f, m1 = 0.f;               // relu floor
        #pragma unroll
        for (int k = 0; k < 16; ++k) {
            const int r = (int)kr[k];           // within-batch row
            const unsigned v = *(const unsigned*)(Zb + ((size_t)(b * NPTS + r)) * CCH + 2 * lane);
            const float z0 = __uint_as_float(v << 16);
            const float z1 = __uint_as_float(v & 0xFFFF0000u);
            m0 = fmaxf(m0, s0 * z0 + t0);
            m1 = fmaxf(m1, s1 * z1 + t1);
        }
        sm[wid * 4 + p][2 * lane]     = m0;
        sm[wid * 4 + p][2 * lane + 1] = m1;
    }
    __syncthreads();

    const int c    = threadIdx.x & 127;
    const int half = threadIdx.x >> 7;
    float v[8];
    #pragma unroll
    for (int i = 0; i < 8; ++i) v[i] = sm[half * 8 + i][c];
    float4 f0 = {v[0], v[1], v[2], v[3]};
    float4 f1 = {v[4], v[5], v[6], v[7]};
    float* op = out + ((size_t)(b * CCH + c)) * NPTS + (n0 & 4095) + half * 8;
    *(float4*)op       = f0;
    *(float4*)(op + 4) = f1;
}

extern "C" void kernel_launch(void* const* d_in, const int* in_sizes, int n_in,
                              void* d_out, int out_size, void* d_ws, size_t ws_size,
                              hipStream_t stream)
{
    const float* xyz   = (const float*)d_in[0];
    const float* x     = (const float*)d_in[1];
    const float* W     = (const float*)d_in[2];
    const float* gamma = (const float*)d_in[3];
    const float* beta  = (const float*)d_in[4];
    const float* rmean = (const float*)d_in[5];
    const float* rvar  = (const float*)d_in[6];
    float* out = (float*)d_out;

    char* ws = (char*)d_ws;
    short*          xTb   = (short*)(ws);
    short*          Wb    = (short*)(ws + 8388608);
    float*          scale = (float*)(ws + 8421376);
    float*          bias  = (float*)(ws + 8421888);
    float4*         pts   = (float4*)(ws + 8422400);
    unsigned short* knn   = (unsigned short*)(ws + 8946688);
    short*          Zb    = (short*)(ws + 9995264);

    // grid scratch overlays Zb (consumed before zgemm writes Zb)
    char* gz = (char*)Zb;
    unsigned*       counts = (unsigned*)(gz);
    unsigned*       fill   = (unsigned*)(gz + 1048576);
    unsigned*       starts = (unsigned*)(gz + 2097152);
    unsigned*       cellid = (unsigned*)(gz + 3145728);
    float4*         psort  = (float4*)(gz + 3276800);
    unsigned short* isort  = (unsigned short*)(gz + 3801088);

    transpose_kernel<<<BATCH * 64 * 2, 256, 0, stream>>>(x, xTb);
    small_prep_kernel<<<BATCH * NPTS / 256, 256, 0, stream>>>(
        xyz, W, gamma, beta, rmean, rvar, Wb, scale, bias, pts);
    zero_kernel<<<512, 256, 0, stream>>>((uint4*)gz);   // counts + fill (2 MB)
    hist_kernel<<<BATCH * NPTS / 256, 256, 0, stream>>>(pts, counts, cellid);
    scan_kernel<<<BATCH, 1024, 0, stream>>>(counts, starts);
    scatter_kernel<<<BATCH * NPTS / 256, 256, 0, stream>>>(
        pts, cellid, starts, fill, psort, isort);
    knn_grid_kernel<<<BATCH * NPTS / 16, 256, 0, stream>>>(
        psort, isort, starts, counts, knn);
    zgemm_kernel<<<BATCH * NPTS / 64, 256, 0, stream>>>(xTb, Wb, Zb);
    gmax_kernel<<<BATCH * NPTS / 16, 256, 0, stream>>>(Zb, knn, scale, bias, out);
}

// Round 6
// 206.548 us; speedup vs baseline: 34.2722x; 34.2722x over previous
//
#include <hip/hip_runtime.h>
#include <hip/hip_bf16.h>

// Problem constants (fixed by the reference)
#define BATCH 8
#define NPTS  4096      // N
#define CCH   128      // C
#define KNN_K 16       // K

// KNN spatial grid: 16^3 cells over [-4.6, 4.6)^3 (N(0,1) outliers clamp)
#define GD  16
#define GC  (GD * GD * GD)      // 4096 cells per batch
#define GLO (-4.6f)
#define GH  (9.2f / 16.0f)      // 0.575
#define GIH (16.0f / 9.2f)

typedef __attribute__((ext_vector_type(8))) short  bf16x8;  // 8 bf16 = 4 VGPRs
typedef __attribute__((ext_vector_type(4))) float  f32x4;   // MFMA acc

// ---------------------------------------------------------------------------
// ws layout (bytes):
//   [0)          xTb   : B*N*C bf16      = 8,388,608
//   [8388608)    Wb    : C*C  bf16       =    32,768
//   [8421376)    scale : C fp32          =       512
//   [8421888)    bias  : C fp32          =       512
//   [8422400)    pts   : B*N float4(x,y,z,s) = 524,288
//   [8946688)    knn   : B*N*K u16       = 1,048,576
//   [9995264)    Zb    : B*N*C bf16      = 8,388,608   (Z = W@x, [B,N,C])
// Grid scratch OVERLAYS Zb (zgemm writes Zb only after knn completes):
//   Zb+0         counts : u32[8*GC]  = 131,072
//   Zb+131072    fill   : u32[8*GC]  = 131,072
//   Zb+262144    starts : u32[8*GC]  = 131,072
//   Zb+393216    cellid : u32[B*N]   = 131,072
//   Zb+524288    psort  : float4[B*N]= 524,288
//   Zb+1048576   isort  : u16[B*N]   =  65,536   (ends 1,114,112 < 8 MB)
// ---------------------------------------------------------------------------

static __device__ __forceinline__ short f2bf(float v) {
    __hip_bfloat16 h = __float2bfloat16(v);   // RNE
    return __builtin_bit_cast(short, h);
}

// LDS-tiled transpose: x [B,C,N] fp32 -> xTb [B,N,C] bf16.
__global__ __launch_bounds__(256) void transpose_kernel(
    const float* __restrict__ x, short* __restrict__ xTb)
{
    __shared__ short tile[64 * 66];
    const int tid = threadIdx.x;
    const int b   = blockIdx.x >> 7;         // 8 batches
    const int rem = blockIdx.x & 127;
    const int nt  = rem >> 1;                // 64 n-tiles of 64
    const int ct  = rem & 1;                 // 2 c-tiles of 64

    #pragma unroll
    for (int it = 0; it < 16; ++it) {
        const int idx = it * 256 + tid;
        const int cc  = idx >> 6;
        const int nn  = idx & 63;
        const float v = x[(size_t)(b * CCH + ct * 64 + cc) * NPTS + nt * 64 + nn];
        tile[cc * 66 + nn] = f2bf(v);
    }
    __syncthreads();
    #pragma unroll
    for (int it = 0; it < 16; ++it) {
        const int idx = it * 256 + tid;
        const int nn  = idx >> 6;
        const int cc  = idx & 63;
        xTb[(size_t)(b * NPTS + nt * 64 + nn) * CCH + ct * 64 + cc] = tile[cc * 66 + nn];
    }
}

// Small prep: W -> bf16; fold BN affine; xyz -> SoA float4 with |p|^2
__global__ __launch_bounds__(256) void small_prep_kernel(
    const float* __restrict__ xyz, const float* __restrict__ W,
    const float* __restrict__ gamma, const float* __restrict__ beta,
    const float* __restrict__ rmean, const float* __restrict__ rvar,
    short* __restrict__ Wb, float* __restrict__ scale, float* __restrict__ bias,
    float4* __restrict__ pts)
{
    const int t = blockIdx.x * 256 + threadIdx.x;   // grid covers B*N = 32768
    if (t < CCH * CCH) Wb[t] = f2bf(W[t]);
    if (t < CCH) {
        const float s = gamma[t] / sqrtf(rvar[t] + 1e-5f);
        scale[t] = s;
        bias[t]  = beta[t] - rmean[t] * s;
    }
    {
        #pragma clang fp contract(off)
        const float px = xyz[3 * t + 0];
        const float py = xyz[3 * t + 1];
        const float pz = xyz[3 * t + 2];
        const float s  = px * px + py * py + pz * pz;   // matches ref s = sum(xyz*xyz)
        pts[t] = make_float4(px, py, pz, s);
    }
}

// ---- grid build ----------------------------------------------------------

__global__ __launch_bounds__(256) void zero_kernel(uint4* __restrict__ p)
{
    p[blockIdx.x * 256 + threadIdx.x] = make_uint4(0, 0, 0, 0);  // 256 KB: counts+fill
}

static __device__ __forceinline__ int cell_of(float v) {
    int c = (int)floorf((v - GLO) * GIH);
    return c < 0 ? 0 : (c > GD - 1 ? GD - 1 : c);
}

__global__ __launch_bounds__(256) void hist_kernel(
    const float4* __restrict__ pts, unsigned* __restrict__ counts,
    unsigned* __restrict__ cellid)
{
    const int t = blockIdx.x * 256 + threadIdx.x;   // B*N
    const float4 p = pts[t];
    const int cell = (cell_of(p.z) * GD + cell_of(p.y)) * GD + cell_of(p.x);
    cellid[t] = (unsigned)cell;
    atomicAdd(&counts[((t >> 12) << 12) + cell], 1u);
}

// exclusive scan of 4096 cell counts per batch; one block per batch
__global__ __launch_bounds__(1024) void scan_kernel(
    const unsigned* __restrict__ counts, unsigned* __restrict__ starts)
{
    __shared__ unsigned part[1024];
    const int b = blockIdx.x, t = threadIdx.x;
    const int base = (b << 12) + t * 4;
    unsigned c0 = counts[base], c1 = counts[base + 1];
    unsigned c2 = counts[base + 2], c3 = counts[base + 3];
    part[t] = c0 + c1 + c2 + c3;
    __syncthreads();
    for (int off = 1; off < 1024; off <<= 1) {
        const unsigned v = (t >= off) ? part[t - off] : 0u;
        __syncthreads();
        part[t] += v;
        __syncthreads();
    }
    unsigned run = (t == 0) ? 0u : part[t - 1];
    starts[base]     = run; run += c0;
    starts[base + 1] = run; run += c1;
    starts[base + 2] = run; run += c2;
    starts[base + 3] = run;
}

__global__ __launch_bounds__(256) void scatter_kernel(
    const float4* __restrict__ pts, const unsigned* __restrict__ cellid,
    const unsigned* __restrict__ starts, unsigned* __restrict__ fill,
    float4* __restrict__ psort, unsigned short* __restrict__ isort)
{
    const int t = blockIdx.x * 256 + threadIdx.x;   // B*N
    const unsigned idx = ((unsigned)(t >> 12) << 12) + cellid[t];
    const unsigned pos = starts[idx] + atomicAdd(&fill[idx], 1u);
    const int d = ((t >> 12) << 12) + (int)pos;
    psort[d] = pts[t];
    isort[d] = (unsigned short)(t & 4095);
}

// ---- grid KNN ------------------------------------------------------------

#define PK_(h, l) ((((unsigned long long)(h)) << 32) | (unsigned long long)(l))

// KNN v6: span-streamed grid traversal + buffered top-k with bitonic flush.
// 4 queries per wave (sorted order), lane = g*16+s; home cell is PER-GROUP
// (q is group-uniform). Traversal: box B1 (27 cells = 9 contiguous row-spans
// of the sorted array), then shell R=2, then a dense fallback for any group
// not yet provably complete. Fallback resets the group's list but keeps tau
// (valid upper bound on the true 16th distance -> cheap mostly-empty ballots).
// Keys are (mono(d2), orig_j): selection order-independent, filter d2<=tau.
// Termination: distance from q to the exterior of its processed box (with
// 1e-4 slack) > tau => remaining cells can't contribute. Clamped boundary
// cells only make this bound more conservative. d2 is the bit-identical
// contract-off reference expression.
__global__ __launch_bounds__(256) void knn_grid_kernel(
    const float4* __restrict__ psort, const unsigned short* __restrict__ isort,
    const unsigned* __restrict__ starts, unsigned short* __restrict__ knn)
{
    const int lane = threadIdx.x & 63;
    const int wid  = threadIdx.x >> 6;
    const int g    = lane >> 4;                 // group (query) 0..3
    const int s    = lane & 15;                 // slot within group
    const int wq   = blockIdx.x * 16 + wid * 4; // first sorted query of wave
    const int b    = wq >> 12;
    const int sp   = (wq & 4095) + g;           // this lane's sorted position
    const float4*         ps  = psort + (b << 12);
    const unsigned short* is  = isort + (b << 12);
    const unsigned*       cst = starts + (b << 12);

    const float4 q  = ps[sp];                   // group-uniform
    const int    qi = (int)is[sp];              // orig within-batch index

    // per-GROUP home cell (group-uniform since q is)
    const int hx = cell_of(q.x), hy = cell_of(q.y), hz = cell_of(q.z);
    const float hlx = GLO + hx * GH;
    const float hly = GLO + hy * GH;
    const float hlz = GLO + hz * GH;

    const unsigned SENT_HI = 0xFF7FFFFFu;       // mono(+3.4e38)
    const unsigned SENT_LO = 0xFFFFFFFFu;

    unsigned lhi = SENT_HI, llo = SENT_LO;      // sorted top-16 list (asc)
    float bufD = 0.f;                           // survivor buffer (slot s)
    int   bufJ = 0;
    int   cnt  = 0;                             // valid entries (group-uniform)
    float tau  = 3.4e38f;
    const int      gsh   = g << 4;
    const unsigned smask = (1u << s) - 1u;

    auto sort16 = [&](unsigned& hi, unsigned& lo) {
        #define CE_(K, J, OFF) { \
            const unsigned ohi = (unsigned)__builtin_amdgcn_ds_swizzle((int)hi, OFF); \
            const unsigned olo = (unsigned)__builtin_amdgcn_ds_swizzle((int)lo, OFF); \
            const bool olt = PK_(ohi, olo) < PK_(hi, lo); \
            const bool sel = (((s & (J)) == 0) == ((s & (K)) == 0)); \
            const bool tk  = sel ? olt : !olt; \
            hi = tk ? ohi : hi; lo = tk ? olo : lo; }
        CE_(2, 1, 0x041F)
        CE_(4, 2, 0x081F)  CE_(4, 1, 0x041F)
        CE_(8, 4, 0x101F)  CE_(8, 2, 0x081F)  CE_(8, 1, 0x041F)
        CE_(16, 8, 0x201F) CE_(16, 4, 0x101F) CE_(16, 2, 0x081F) CE_(16, 1, 0x041F)
        #undef CE_
    };

    auto refresh_tau = [&]() {
        const unsigned thi = (unsigned)__builtin_amdgcn_ds_swizzle((int)lhi, 0x01F0);
        tau = __uint_as_float((thi & 0x80000000u) ? (thi & 0x7FFFFFFFu) : ~thi);
    };

    auto flush = [&]() {
        const unsigned u = __float_as_uint(bufD);
        unsigned khi = (u & 0x80000000u) ? ~u : (u | 0x80000000u);
        unsigned klo = (unsigned)bufJ;
        const bool inval = (s >= cnt);
        khi = inval ? SENT_HI : khi;
        klo = inval ? SENT_LO : klo;
        sort16(khi, klo);
        {
            const unsigned rhi = (unsigned)__builtin_amdgcn_ds_swizzle((int)khi, 0x3C1F);
            const unsigned rlo = (unsigned)__builtin_amdgcn_ds_swizzle((int)klo, 0x3C1F);
            const bool rlt = PK_(rhi, rlo) < PK_(lhi, llo);
            lhi = rlt ? rhi : lhi; llo = rlt ? rlo : llo;
        }
        #define MC_(J, OFF) { \
            const unsigned ohi = (unsigned)__builtin_amdgcn_ds_swizzle((int)lhi, OFF); \
            const unsigned olo = (unsigned)__builtin_amdgcn_ds_swizzle((int)llo, OFF); \
            const bool olt = PK_(ohi, olo) < PK_(lhi, llo); \
            const bool tk  = ((s & (J)) == 0) ? olt : !olt; \
            lhi = tk ? ohi : lhi; llo = tk ? olo : llo; }
        MC_(8, 0x201F) MC_(4, 0x101F) MC_(2, 0x081F) MC_(1, 0x041F)
        #undef MC_
        refresh_tau();
        cnt = 0;
    };

    auto append = [&](float d2v, int jov) {
        const unsigned long long mask = __ballot(d2v <= tau);
        if (mask) {
            const unsigned sub = (unsigned)((mask >> gsh) & 0xFFFFull);
            const int m = __popc(sub);
            const int lim = 15 + (m >> 4);      // m==16 needs no parking slot
            if (__any(cnt + m > lim)) flush();
            const bool surv = (sub >> s) & 1u;
            const int rank  = __popc(sub & smask);
            const int dest  = surv ? (cnt + rank) : 15;
            const int addr  = (gsh | dest) << 2;
            const int nd = __builtin_amdgcn_ds_permute(addr, __float_as_int(d2v));
            const int nj = __builtin_amdgcn_ds_permute(addr, jov);
            const bool got = (s >= cnt) & (s < cnt + m);
            bufD = got ? __int_as_float(nd) : bufD;
            bufJ = got ? nj : bufJ;
            cnt += m;
        }
    };

    // process cells [x0..x1] of row (zz,yy): ONE contiguous sorted range
    auto span = [&](int zz, int yy, int x0, int x1) {
        const int cb = (zz * GD + yy) * GD;
        const unsigned st = cst[cb + x0];
        const unsigned en = (cb + x1 + 1 < GC) ? cst[cb + x1 + 1] : (unsigned)NPTS;
        for (unsigned c0 = st; c0 < en; c0 += 16) {
            const unsigned idx = c0 + (unsigned)s;
            float d2 = __builtin_inff();
            int   jo = 0;
            if (idx < en) {
                const float4 p = ps[idx];
                jo = (int)is[idx];
                {
                    #pragma clang fp contract(off)
                    d2 = (q.w + p.w) - 2.0f * (q.x * p.x + q.y * p.y + q.z * p.z);
                }
            }
            append(d2, jo);
        }
    };

    // true iff no cell outside box B_R (home dilated R) can hold a candidate
    auto done_after = [&](int R) -> bool {
        const float e  = (float)R * GH;
        const float m1 = fminf(q.x - (hlx - e), (hlx + GH + e) - q.x);
        const float m2 = fminf(q.y - (hly - e), (hly + GH + e) - q.y);
        const float m3 = fminf(q.z - (hlz - e), (hlz + GH + e) - q.z);
        const float dm = fmaxf(fminf(m1, fminf(m2, m3)) - 1e-4f, 0.f);
        return dm * dm > tau;
    };

    // ---- box B1: 9 row-spans (clamped)
    {
        const int z0 = max(hz - 1, 0), z1 = min(hz + 1, GD - 1);
        const int y0 = max(hy - 1, 0), y1 = min(hy + 1, GD - 1);
        const int x0 = max(hx - 1, 0), x1 = min(hx + 1, GD - 1);
        for (int zz = z0; zz <= z1; ++zz)
            for (int yy = y0; yy <= y1; ++yy)
                span(zz, yy, x0, x1);
    }
    if (__any(cnt != 0)) flush();
    bool gdone = done_after(1);

    // ---- shell R=2 for unfinished groups
    if (!__all(gdone)) {
        if (!gdone) {
            const int x0 = max(hx - 2, 0), x1 = min(hx + 2, GD - 1);
            for (int dz = -2; dz <= 2; ++dz) {
                const int zz = hz + dz;
                if ((unsigned)zz >= GD) continue;
                const bool zface = (dz == -2) | (dz == 2);
                for (int dy = -2; dy <= 2; ++dy) {
                    const int yy = hy + dy;
                    if ((unsigned)yy >= GD) continue;
                    if (zface | (dy == -2) | (dy == 2)) {
                        span(zz, yy, x0, x1);
                    } else {
                        if (hx - 2 >= 0)     span(zz, yy, hx - 2, hx - 2);
                        if (hx + 2 <= GD - 1) span(zz, yy, hx + 2, hx + 2);
                    }
                }
            }
        }
        if (__any(cnt != 0)) flush();
        gdone = gdone || done_after(2);
    }

    // ---- dense fallback for any group still not provably complete.
    // Reset its list (avoids duplicate keys) but KEEP tau: it upper-bounds
    // the true 16th distance, so the <=tau ballot filters almost everything.
    if (!__all(gdone)) {
        if (!gdone) { lhi = SENT_HI; llo = SENT_LO; }
        for (unsigned c0 = 0; c0 < (unsigned)NPTS; c0 += 16) {
            float d2 = __builtin_inff();
            int   jo = 0;
            if (!gdone) {
                const unsigned idx = c0 + (unsigned)s;
                const float4 p = ps[idx];
                jo = (int)is[idx];
                {
                    #pragma clang fp contract(off)
                    d2 = (q.w + p.w) - 2.0f * (q.x * p.x + q.y * p.y + q.z * p.z);
                }
            }
            append(d2, jo);
        }
        if (__any(cnt != 0)) flush();
    }

    unsigned short* o = knn + ((((size_t)b << 12) + qi) << 4);
    o[s] = (unsigned short)llo;                 // j of s-th smallest (d2, j)
}

// Dense GEMM: Z[g, c] = sum_k xTb[g, k] * W[c, k], Z bf16 [B*N, C].
__global__ __launch_bounds__(256) void zgemm_kernel(
    const short* __restrict__ xTb, const short* __restrict__ Wb,
    short* __restrict__ Zb)
{
    __shared__ short sW[CCH * 136];
    const int lane = threadIdx.x & 63;
    const int wid  = threadIdx.x >> 6;
    const int kl   = lane & 15;
    const int q8   = (lane >> 4) * 8;

    #pragma unroll
    for (int it = 0; it < 8; ++it) {             // stage W: 16384 elems
        const int e = (it * 256 + threadIdx.x) * 8;
        const int r = e >> 7, c = e & 127;
        *(bf16x8*)(sW + r * 136 + c) = *(const bf16x8*)(Wb + e);
    }

    const int    G    = blockIdx.x * 64 + wid * 16 + kl;   // A-row (flat B*N)
    const size_t arow = (size_t)G * CCH;
    __syncthreads();

    const f32x4 zero = {0.f, 0.f, 0.f, 0.f};
    f32x4 acc[8];
    #pragma unroll
    for (int t = 0; t < 8; ++t) acc[t] = zero;

    #pragma unroll
    for (int kk = 0; kk < 4; ++kk) {
        const bf16x8 a = *(const bf16x8*)(xTb + arow + kk * 32 + q8);
        #pragma unroll
        for (int t = 0; t < 8; ++t) {
            const bf16x8 bf = *(const bf16x8*)(sW + (t * 16 + kl) * 136 + kk * 32 + q8);
            acc[t] = __builtin_amdgcn_mfma_f32_16x16x32_bf16(a, bf, acc[t], 0, 0, 0);
        }
    }

    const int rbase = blockIdx.x * 64 + wid * 16 + (lane >> 4) * 4;
    #pragma unroll
    for (int t = 0; t < 8; ++t)
        #pragma unroll
        for (int r = 0; r < 4; ++r)
            Zb[(size_t)(rbase + r) * CCH + t * 16 + kl] = f2bf(acc[t][r]);
}

// Gather + BN + ReLU + max-over-16, then coalesced store via LDS transpose.
__global__ __launch_bounds__(256) void gmax_kernel(
    const short* __restrict__ Zb, const unsigned short* __restrict__ knn,
    const float* __restrict__ scale, const float* __restrict__ bias,
    float* __restrict__ out)
{
    __shared__ float sm[16][132];
    const int lane = threadIdx.x & 63;
    const int wid  = threadIdx.x >> 6;
    const int n0   = blockIdx.x * 16;           // flat point base (B*N)
    const int b    = blockIdx.x >> 8;           // 256 blocks per batch
    const float s0 = scale[2 * lane],   s1 = scale[2 * lane + 1];
    const float t0 = bias[2 * lane],    t1 = bias[2 * lane + 1];

    for (int p = 0; p < 4; ++p) {
        const int n = n0 + wid * 4 + p;         // flat
        const unsigned short* kr = knn + (size_t)n * 16;
        float m0 = 0.f, m1 = 0.f;               // relu floor
        #pragma unroll
        for (int k = 0; k < 16; ++k) {
            const int r = (int)kr[k];           // within-batch row
            const unsigned v = *(const unsigned*)(Zb + ((size_t)(b * NPTS + r)) * CCH + 2 * lane);
            const float z0 = __uint_as_float(v << 16);
            const float z1 = __uint_as_float(v & 0xFFFF0000u);
            m0 = fmaxf(m0, s0 * z0 + t0);
            m1 = fmaxf(m1, s1 * z1 + t1);
        }
        sm[wid * 4 + p][2 * lane]     = m0;
        sm[wid * 4 + p][2 * lane + 1] = m1;
    }
    __syncthreads();

    const int c    = threadIdx.x & 127;
    const int half = threadIdx.x >> 7;
    float v[8];
    #pragma unroll
    for (int i = 0; i < 8; ++i) v[i] = sm[half * 8 + i][c];
    float4 f0 = {v[0], v[1], v[2], v[3]};
    float4 f1 = {v[4], v[5], v[6], v[7]};
    float* op = out + ((size_t)(b * CCH + c)) * NPTS + (n0 & 4095) + half * 8;
    *(float4*)op       = f0;
    *(float4*)(op + 4) = f1;
}

extern "C" void kernel_launch(void* const* d_in, const int* in_sizes, int n_in,
                              void* d_out, int out_size, void* d_ws, size_t ws_size,
                              hipStream_t stream)
{
    const float* xyz   = (const float*)d_in[0];
    const float* x     = (const float*)d_in[1];
    const float* W     = (const float*)d_in[2];
    const float* gamma = (const float*)d_in[3];
    const float* beta  = (const float*)d_in[4];
    const float* rmean = (const float*)d_in[5];
    const float* rvar  = (const float*)d_in[6];
    float* out = (float*)d_out;

    char* ws = (char*)d_ws;
    short*          xTb   = (short*)(ws);
    short*          Wb    = (short*)(ws + 8388608);
    float*          scale = (float*)(ws + 8421376);
    float*          bias  = (float*)(ws + 8421888);
    float4*         pts   = (float4*)(ws + 8422400);
    unsigned short* knn   = (unsigned short*)(ws + 8946688);
    short*          Zb    = (short*)(ws + 9995264);

    // grid scratch overlays Zb (consumed before zgemm writes Zb)
    char* gz = (char*)Zb;
    unsigned*       counts = (unsigned*)(gz);
    unsigned*       fill   = (unsigned*)(gz + 131072);
    unsigned*       starts = (unsigned*)(gz + 262144);
    unsigned*       cellid = (unsigned*)(gz + 393216);
    float4*         psort  = (float4*)(gz + 524288);
    unsigned short* isort  = (unsigned short*)(gz + 1048576);

    transpose_kernel<<<BATCH * 64 * 2, 256, 0, stream>>>(x, xTb);
    small_prep_kernel<<<BATCH * NPTS / 256, 256, 0, stream>>>(
        xyz, W, gamma, beta, rmean, rvar, Wb, scale, bias, pts);
    zero_kernel<<<64, 256, 0, stream>>>((uint4*)gz);   // counts + fill (256 KB)
    hist_kernel<<<BATCH * NPTS / 256, 256, 0, stream>>>(pts, counts, cellid);
    scan_kernel<<<BATCH, 1024, 0, stream>>>(counts, starts);
    scatter_kernel<<<BATCH * NPTS / 256, 256, 0, stream>>>(
        pts, cellid, starts, fill, psort, isort);
    knn_grid_kernel<<<BATCH * NPTS / 16, 256, 0, stream>>>(
        psort, isort, starts, knn);
    zgemm_kernel<<<BATCH * NPTS / 64, 256, 0, stream>>>(xTb, Wb, Zb);
    gmax_kernel<<<BATCH * NPTS / 16, 256, 0, stream>>>(Zb, knn, scale, bias, out);
}

// Round 7
// 197.751 us; speedup vs baseline: 35.7968x; 1.0445x over previous
//
#include <hip/hip_runtime.h>
#include <hip/hip_bf16.h>

// Problem constants (fixed by the reference)
#define BATCH 8
#define NPTS  4096      // N
#define CCH   128      // C
#define KNN_K 16       // K

// KNN spatial grid: 16^3 cells over [-4.6, 4.6)^3 (N(0,1) outliers clamp)
#define GD  16
#define GC  (GD * GD * GD)      // 4096 cells per batch
#define GLO (-4.6f)
#define GH  (9.2f / 16.0f)      // 0.575
#define GIH (16.0f / 9.2f)

typedef __attribute__((ext_vector_type(8))) short  bf16x8;  // 8 bf16 = 4 VGPRs
typedef __attribute__((ext_vector_type(4))) float  f32x4;   // MFMA acc

// ---------------------------------------------------------------------------
// ws layout (bytes):
//   [0)          xTb   : B*N*C bf16      = 8,388,608
//   [8388608)    Wb    : C*C  bf16       =    32,768
//   [8421376)    scale : C fp32          =       512
//   [8421888)    bias  : C fp32          =       512
//   [8422400)    pts   : B*N float4(x,y,z,s) = 524,288
//   [8946688)    knn   : B*N*K u16       = 1,048,576
//   [9995264)    Zb    : B*N*C bf16      = 8,388,608   (Z = W@x, [B,N,C])
// Grid scratch OVERLAYS Zb (zgemm writes Zb only after knn completes):
//   Zb+0         counts : u32[8*GC]  = 131,072
//   Zb+131072    fill   : u32[8*GC]  = 131,072
//   Zb+262144    starts : u32[8*GC]  = 131,072
//   Zb+393216    cellid : u32[B*N]   = 131,072
//   Zb+524288    psort  : float4[B*N]= 524,288
//   Zb+1048576   isort  : u16[B*N]   =  65,536   (ends 1,114,112 < 8 MB)
// ---------------------------------------------------------------------------

static __device__ __forceinline__ short f2bf(float v) {
    __hip_bfloat16 h = __float2bfloat16(v);   // RNE
    return __builtin_bit_cast(short, h);
}

// LDS-tiled transpose: x [B,C,N] fp32 -> xTb [B,N,C] bf16.
__global__ __launch_bounds__(256) void transpose_kernel(
    const float* __restrict__ x, short* __restrict__ xTb)
{
    __shared__ short tile[64 * 66];
    const int tid = threadIdx.x;
    const int b   = blockIdx.x >> 7;         // 8 batches
    const int rem = blockIdx.x & 127;
    const int nt  = rem >> 1;                // 64 n-tiles of 64
    const int ct  = rem & 1;                 // 2 c-tiles of 64

    #pragma unroll
    for (int it = 0; it < 16; ++it) {
        const int idx = it * 256 + tid;
        const int cc  = idx >> 6;
        const int nn  = idx & 63;
        const float v = x[(size_t)(b * CCH + ct * 64 + cc) * NPTS + nt * 64 + nn];
        tile[cc * 66 + nn] = f2bf(v);
    }
    __syncthreads();
    #pragma unroll
    for (int it = 0; it < 16; ++it) {
        const int idx = it * 256 + tid;
        const int nn  = idx >> 6;
        const int cc  = idx & 63;
        xTb[(size_t)(b * NPTS + nt * 64 + nn) * CCH + ct * 64 + cc] = tile[cc * 66 + nn];
    }
}

// Small prep: W -> bf16; fold BN affine; xyz -> SoA float4 with |p|^2
__global__ __launch_bounds__(256) void small_prep_kernel(
    const float* __restrict__ xyz, const float* __restrict__ W,
    const float* __restrict__ gamma, const float* __restrict__ beta,
    const float* __restrict__ rmean, const float* __restrict__ rvar,
    short* __restrict__ Wb, float* __restrict__ scale, float* __restrict__ bias,
    float4* __restrict__ pts)
{
    const int t = blockIdx.x * 256 + threadIdx.x;   // grid covers B*N = 32768
    if (t < CCH * CCH) Wb[t] = f2bf(W[t]);
    if (t < CCH) {
        const float s = gamma[t] / sqrtf(rvar[t] + 1e-5f);
        scale[t] = s;
        bias[t]  = beta[t] - rmean[t] * s;
    }
    {
        #pragma clang fp contract(off)
        const float px = xyz[3 * t + 0];
        const float py = xyz[3 * t + 1];
        const float pz = xyz[3 * t + 2];
        const float s  = px * px + py * py + pz * pz;   // matches ref s = sum(xyz*xyz)
        pts[t] = make_float4(px, py, pz, s);
    }
}

// ---- grid build ----------------------------------------------------------

__global__ __launch_bounds__(256) void zero_kernel(uint4* __restrict__ p)
{
    p[blockIdx.x * 256 + threadIdx.x] = make_uint4(0, 0, 0, 0);  // 256 KB: counts+fill
}

static __device__ __forceinline__ int cell_of(float v) {
    int c = (int)floorf((v - GLO) * GIH);
    return c < 0 ? 0 : (c > GD - 1 ? GD - 1 : c);
}

__global__ __launch_bounds__(256) void hist_kernel(
    const float4* __restrict__ pts, unsigned* __restrict__ counts,
    unsigned* __restrict__ cellid)
{
    const int t = blockIdx.x * 256 + threadIdx.x;   // B*N
    const float4 p = pts[t];
    const int cell = (cell_of(p.z) * GD + cell_of(p.y)) * GD + cell_of(p.x);
    cellid[t] = (unsigned)cell;
    atomicAdd(&counts[((t >> 12) << 12) + cell], 1u);
}

// exclusive scan of 4096 cell counts per batch; one block per batch
__global__ __launch_bounds__(1024) void scan_kernel(
    const unsigned* __restrict__ counts, unsigned* __restrict__ starts)
{
    __shared__ unsigned part[1024];
    const int b = blockIdx.x, t = threadIdx.x;
    const int base = (b << 12) + t * 4;
    unsigned c0 = counts[base], c1 = counts[base + 1];
    unsigned c2 = counts[base + 2], c3 = counts[base + 3];
    part[t] = c0 + c1 + c2 + c3;
    __syncthreads();
    for (int off = 1; off < 1024; off <<= 1) {
        const unsigned v = (t >= off) ? part[t - off] : 0u;
        __syncthreads();
        part[t] += v;
        __syncthreads();
    }
    unsigned run = (t == 0) ? 0u : part[t - 1];
    starts[base]     = run; run += c0;
    starts[base + 1] = run; run += c1;
    starts[base + 2] = run; run += c2;
    starts[base + 3] = run;
}

__global__ __launch_bounds__(256) void scatter_kernel(
    const float4* __restrict__ pts, const unsigned* __restrict__ cellid,
    const unsigned* __restrict__ starts, unsigned* __restrict__ fill,
    float4* __restrict__ psort, unsigned short* __restrict__ isort)
{
    const int t = blockIdx.x * 256 + threadIdx.x;   // B*N
    const unsigned idx = ((unsigned)(t >> 12) << 12) + cellid[t];
    const unsigned pos = starts[idx] + atomicAdd(&fill[idx], 1u);
    const int d = ((t >> 12) << 12) + (int)pos;
    psort[d] = pts[t];
    isort[d] = (unsigned short)(t & 4095);
}

// ---- grid KNN ------------------------------------------------------------

#define PK_(h, l) ((((unsigned long long)(h)) << 32) | (unsigned long long)(l))

// KNN v7: WAVE-UNIFORM traversal (fix for R6's divergence/latency collapse).
// 4 queries per wave (sorted order), lane = g*16+s. Home cell = lane 0's
// query cell (wave-uniform -> uniform loop bounds, broadcast metadata).
// Row (st,en) metadata for B1 (9 rows) / R2 shell (25 rows) is fetched by
// lanes IN PARALLEL (one memory round-trip) and distributed via __shfl.
// Termination bound: distance from q (per-group) to the exterior of the
// TRAVERSED wave box, clamped at 0 -> conservative-correct for groups whose
// cell differs from lane 0's (they converge at R=2, or fall through to the
// dense fallback). Dense fallback: reset group list, keep tau (finite after
// B1+B2 except ultra-rare outliers, where flush-refreshed tau self-tightens).
// Selection machinery (append/sort16/flush, keys (mono(d2), orig_j)) is
// byte-identical to the R6-verified version; d2 is the bit-identical
// contract-off reference expression.
__global__ __launch_bounds__(256) void knn_grid_kernel(
    const float4* __restrict__ psort, const unsigned short* __restrict__ isort,
    const unsigned* __restrict__ starts, unsigned short* __restrict__ knn)
{
    const int lane = threadIdx.x & 63;
    const int wid  = threadIdx.x >> 6;
    const int g    = lane >> 4;                 // group (query) 0..3
    const int s    = lane & 15;                 // slot within group
    const int wq   = blockIdx.x * 16 + wid * 4; // first sorted query of wave
    const int b    = wq >> 12;
    const int sp   = (wq & 4095) + g;           // this lane's sorted position
    const float4*         ps  = psort + (b << 12);
    const unsigned short* is  = isort + (b << 12);
    const unsigned*       cst = starts + (b << 12);

    const float4 q  = ps[sp];                   // group-uniform
    const int    qi = (int)is[sp];              // orig within-batch index

    // WAVE-uniform home cell (lane 0's query)
    int hx = cell_of(q.x), hy = cell_of(q.y), hz = cell_of(q.z);
    hx = __shfl(hx, 0); hy = __shfl(hy, 0); hz = __shfl(hz, 0);
    const float hlx = GLO + hx * GH;
    const float hly = GLO + hy * GH;
    const float hlz = GLO + hz * GH;

    const unsigned SENT_HI = 0xFF7FFFFFu;       // mono(+3.4e38)
    const unsigned SENT_LO = 0xFFFFFFFFu;

    unsigned lhi = SENT_HI, llo = SENT_LO;      // sorted top-16 list (asc)
    float bufD = 0.f;                           // survivor buffer (slot s)
    int   bufJ = 0;
    int   cnt  = 0;                             // valid entries (group-uniform)
    float tau  = 3.4e38f;
    const int      gsh   = g << 4;
    const unsigned smask = (1u << s) - 1u;

    auto sort16 = [&](unsigned& hi, unsigned& lo) {
        #define CE_(K, J, OFF) { \
            const unsigned ohi = (unsigned)__builtin_amdgcn_ds_swizzle((int)hi, OFF); \
            const unsigned olo = (unsigned)__builtin_amdgcn_ds_swizzle((int)lo, OFF); \
            const bool olt = PK_(ohi, olo) < PK_(hi, lo); \
            const bool sel = (((s & (J)) == 0) == ((s & (K)) == 0)); \
            const bool tk  = sel ? olt : !olt; \
            hi = tk ? ohi : hi; lo = tk ? olo : lo; }
        CE_(2, 1, 0x041F)
        CE_(4, 2, 0x081F)  CE_(4, 1, 0x041F)
        CE_(8, 4, 0x101F)  CE_(8, 2, 0x081F)  CE_(8, 1, 0x041F)
        CE_(16, 8, 0x201F) CE_(16, 4, 0x101F) CE_(16, 2, 0x081F) CE_(16, 1, 0x041F)
        #undef CE_
    };

    auto refresh_tau = [&]() {
        const unsigned thi = (unsigned)__builtin_amdgcn_ds_swizzle((int)lhi, 0x01F0);
        tau = __uint_as_float((thi & 0x80000000u) ? (thi & 0x7FFFFFFFu) : ~thi);
    };

    auto flush = [&]() {
        const unsigned u = __float_as_uint(bufD);
        unsigned khi = (u & 0x80000000u) ? ~u : (u | 0x80000000u);
        unsigned klo = (unsigned)bufJ;
        const bool inval = (s >= cnt);
        khi = inval ? SENT_HI : khi;
        klo = inval ? SENT_LO : klo;
        sort16(khi, klo);
        {
            const unsigned rhi = (unsigned)__builtin_amdgcn_ds_swizzle((int)khi, 0x3C1F);
            const unsigned rlo = (unsigned)__builtin_amdgcn_ds_swizzle((int)klo, 0x3C1F);
            const bool rlt = PK_(rhi, rlo) < PK_(lhi, llo);
            lhi = rlt ? rhi : lhi; llo = rlt ? rlo : llo;
        }
        #define MC_(J, OFF) { \
            const unsigned ohi = (unsigned)__builtin_amdgcn_ds_swizzle((int)lhi, OFF); \
            const unsigned olo = (unsigned)__builtin_amdgcn_ds_swizzle((int)llo, OFF); \
            const bool olt = PK_(ohi, olo) < PK_(lhi, llo); \
            const bool tk  = ((s & (J)) == 0) ? olt : !olt; \
            lhi = tk ? ohi : lhi; llo = tk ? olo : llo; }
        MC_(8, 0x201F) MC_(4, 0x101F) MC_(2, 0x081F) MC_(1, 0x041F)
        #undef MC_
        refresh_tau();
        cnt = 0;
    };

    auto append = [&](float d2v, int jov) {
        const unsigned long long mask = __ballot(d2v <= tau);
        if (mask) {
            const unsigned sub = (unsigned)((mask >> gsh) & 0xFFFFull);
            const int m = __popc(sub);
            const int lim = 15 + (m >> 4);      // m==16 needs no parking slot
            if (__any(cnt + m > lim)) flush();
            const bool surv = (sub >> s) & 1u;
            const int rank  = __popc(sub & smask);
            const int dest  = surv ? (cnt + rank) : 15;
            const int addr  = (gsh | dest) << 2;
            const int nd = __builtin_amdgcn_ds_permute(addr, __float_as_int(d2v));
            const int nj = __builtin_amdgcn_ds_permute(addr, jov);
            const bool got = (s >= cnt) & (s < cnt + m);
            bufD = got ? __int_as_float(nd) : bufD;
            bufJ = got ? nj : bufJ;
            cnt += m;
        }
    };

    // stream one contiguous sorted range [st, en)
    auto stream = [&](unsigned st, unsigned en) {
        for (unsigned c0 = st; c0 < en; c0 += 16) {
            const unsigned idx = c0 + (unsigned)s;
            float d2 = __builtin_inff();
            int   jo = 0;
            if (idx < en) {
                const float4 p = ps[idx];
                jo = (int)is[idx];
                {
                    #pragma clang fp contract(off)
                    d2 = (q.w + p.w) - 2.0f * (q.x * p.x + q.y * p.y + q.z * p.z);
                }
            }
            append(d2, jo);
        }
    };

    // true iff no cell outside the traversed wave box B_R can contribute
    auto done_after = [&](int R) -> bool {
        const float e  = (float)R * GH;
        const float m1 = fminf(q.x - (hlx - e), (hlx + GH + e) - q.x);
        const float m2 = fminf(q.y - (hly - e), (hly + GH + e) - q.y);
        const float m3 = fminf(q.z - (hlz - e), (hlz + GH + e) - q.z);
        const float dm = fmaxf(fminf(m1, fminf(m2, m3)) - 1e-4f, 0.f);
        return dm * dm > tau;
    };

    // ---- B1: 9 rows; metadata fetched by lanes 0..8 in parallel
    {
        const int x0 = max(hx - 1, 0), x1 = min(hx + 1, GD - 1);
        unsigned rst = 0, ren = 0; int rok = 0;
        if (lane < 9) {
            const int zz = hz + lane / 3 - 1;
            const int yy = hy + lane % 3 - 1;
            if ((unsigned)zz < GD && (unsigned)yy < GD) {
                const int cb = (zz * GD + yy) * GD;
                rst = cst[cb + x0];
                ren = (cb + x1 + 1 < GC) ? cst[cb + x1 + 1] : (unsigned)NPTS;
                rok = 1;
            }
        }
        #pragma unroll 1
        for (int r = 0; r < 9; ++r) {
            if (__shfl(rok, r)) stream(__shfl(rst, r), __shfl(ren, r));
        }
    }
    if (__any(cnt != 0)) flush();
    bool gdone = done_after(1);

    // ---- shell R=2 (wave-uniform): 25 rows; 16 full rows + 9 interior rows
    // with two single-cell spans (x = hx-2 and hx+2). Metadata via lanes 0..24.
    if (!__all(gdone)) {
        const int xs0 = max(hx - 2, 0), xs1 = min(hx + 2, GD - 1);
        unsigned fst = 0, fen = 0, lst = 0, len = 0, rst2 = 0, ren2 = 0;
        int kind = 0;                           // 0=skip, 1=full row, 2=two singles
        if (lane < 25) {
            const int dz = lane / 5 - 2, dy = lane % 5 - 2;
            const int zz = hz + dz, yy = hy + dy;
            if ((unsigned)zz < GD && (unsigned)yy < GD) {
                const int cb = (zz * GD + yy) * GD;
                const bool full = (dz == -2) | (dz == 2) | (dy == -2) | (dy == 2);
                if (full) {
                    kind = 1;
                    fst = cst[cb + xs0];
                    fen = (cb + xs1 + 1 < GC) ? cst[cb + xs1 + 1] : (unsigned)NPTS;
                } else {
                    kind = 2;
                    if (hx - 2 >= 0) {
                        lst = cst[cb + hx - 2];
                        len = cst[cb + hx - 1];
                    }
                    if (hx + 2 <= GD - 1) {
                        rst2 = cst[cb + hx + 2];
                        ren2 = (cb + hx + 3 < GC) ? cst[cb + hx + 3] : (unsigned)NPTS;
                    }
                }
            }
        }
        #pragma unroll 1
        for (int r = 0; r < 25; ++r) {
            const int k = __shfl(kind, r);
            if (k == 1) {
                stream(__shfl(fst, r), __shfl(fen, r));
            } else if (k == 2) {
                const unsigned sa = __shfl(lst, r),  sb = __shfl(len, r);
                if (sa < sb) stream(sa, sb);
                const unsigned sc = __shfl(rst2, r), sd = __shfl(ren2, r);
                if (sc < sd) stream(sc, sd);
            }
        }
        if (__any(cnt != 0)) flush();
        gdone = gdone || done_after(2);
    }

    // ---- dense fallback for any group still not provably complete.
    // Reset its list (avoids duplicate keys) but KEEP tau: valid upper bound
    // on the true 16th distance -> cheap mostly-empty ballots; if tau is
    // still huge (ultra-rare outlier), flush-refreshed tau self-tightens.
    if (!__all(gdone)) {
        if (!gdone) { lhi = SENT_HI; llo = SENT_LO; }
        for (unsigned c0 = 0; c0 < (unsigned)NPTS; c0 += 16) {
            float d2 = __builtin_inff();
            int   jo = 0;
            if (!gdone) {
                const unsigned idx = c0 + (unsigned)s;
                const float4 p = ps[idx];
                jo = (int)is[idx];
                {
                    #pragma clang fp contract(off)
                    d2 = (q.w + p.w) - 2.0f * (q.x * p.x + q.y * p.y + q.z * p.z);
                }
            }
            append(d2, jo);
        }
        if (__any(cnt != 0)) flush();
    }

    unsigned short* o = knn + ((((size_t)b << 12) + qi) << 4);
    o[s] = (unsigned short)llo;                 // j of s-th smallest (d2, j)
}

// Dense GEMM: Z[g, c] = sum_k xTb[g, k] * W[c, k], Z bf16 [B*N, C].
__global__ __launch_bounds__(256) void zgemm_kernel(
    const short* __restrict__ xTb, const short* __restrict__ Wb,
    short* __restrict__ Zb)
{
    __shared__ short sW[CCH * 136];
    const int lane = threadIdx.x & 63;
    const int wid  = threadIdx.x >> 6;
    const int kl   = lane & 15;
    const int q8   = (lane >> 4) * 8;

    #pragma unroll
    for (int it = 0; it < 8; ++it) {             // stage W: 16384 elems
        const int e = (it * 256 + threadIdx.x) * 8;
        const int r = e >> 7, c = e & 127;
        *(bf16x8*)(sW + r * 136 + c) = *(const bf16x8*)(Wb + e);
    }

    const int    G    = blockIdx.x * 64 + wid * 16 + kl;   // A-row (flat B*N)
    const size_t arow = (size_t)G * CCH;
    __syncthreads();

    const f32x4 zero = {0.f, 0.f, 0.f, 0.f};
    f32x4 acc[8];
    #pragma unroll
    for (int t = 0; t < 8; ++t) acc[t] = zero;

    #pragma unroll
    for (int kk = 0; kk < 4; ++kk) {
        const bf16x8 a = *(const bf16x8*)(xTb + arow + kk * 32 + q8);
        #pragma unroll
        for (int t = 0; t < 8; ++t) {
            const bf16x8 bf = *(const bf16x8*)(sW + (t * 16 + kl) * 136 + kk * 32 + q8);
            acc[t] = __builtin_amdgcn_mfma_f32_16x16x32_bf16(a, bf, acc[t], 0, 0, 0);
        }
    }

    const int rbase = blockIdx.x * 64 + wid * 16 + (lane >> 4) * 4;
    #pragma unroll
    for (int t = 0; t < 8; ++t)
        #pragma unroll
        for (int r = 0; r < 4; ++r)
            Zb[(size_t)(rbase + r) * CCH + t * 16 + kl] = f2bf(acc[t][r]);
}

// Gather + BN + ReLU + max-over-16, then coalesced store via LDS transpose.
__global__ __launch_bounds__(256) void gmax_kernel(
    const short* __restrict__ Zb, const unsigned short* __restrict__ knn,
    const float* __restrict__ scale, const float* __restrict__ bias,
    float* __restrict__ out)
{
    __shared__ float sm[16][132];
    const int lane = threadIdx.x & 63;
    const int wid  = threadIdx.x >> 6;
    const int n0   = blockIdx.x * 16;           // flat point base (B*N)
    const int b    = blockIdx.x >> 8;           // 256 blocks per batch
    const float s0 = scale[2 * lane],   s1 = scale[2 * lane + 1];
    const float t0 = bias[2 * lane],    t1 = bias[2 * lane + 1];

    for (int p = 0; p < 4; ++p) {
        const int n = n0 + wid * 4 + p;         // flat
        const unsigned short* kr = knn + (size_t)n * 16;
        float m0 = 0.f, m1 = 0.f;               // relu floor
        #pragma unroll
        for (int k = 0; k < 16; ++k) {
            const int r = (int)kr[k];           // within-batch row
            const unsigned v = *(const unsigned*)(Zb + ((size_t)(b * NPTS + r)) * CCH + 2 * lane);
            const float z0 = __uint_as_float(v << 16);
            const float z1 = __uint_as_float(v & 0xFFFF0000u);
            m0 = fmaxf(m0, s0 * z0 + t0);
            m1 = fmaxf(m1, s1 * z1 + t1);
        }
        sm[wid * 4 + p][2 * lane]     = m0;
        sm[wid * 4 + p][2 * lane + 1] = m1;
    }
    __syncthreads();

    const int c    = threadIdx.x & 127;
    const int half = threadIdx.x >> 7;
    float v[8];
    #pragma unroll
    for (int i = 0; i < 8; ++i) v[i] = sm[half * 8 + i][c];
    float4 f0 = {v[0], v[1], v[2], v[3]};
    float4 f1 = {v[4], v[5], v[6], v[7]};
    float* op = out + ((size_t)(b * CCH + c)) * NPTS + (n0 & 4095) + half * 8;
    *(float4*)op       = f0;
    *(float4*)(op + 4) = f1;
}

extern "C" void kernel_launch(void* const* d_in, const int* in_sizes, int n_in,
                              void* d_out, int out_size, void* d_ws, size_t ws_size,
                              hipStream_t stream)
{
    const float* xyz   = (const float*)d_in[0];
    const float* x     = (const float*)d_in[1];
    const float* W     = (const float*)d_in[2];
    const float* gamma = (const float*)d_in[3];
    const float* beta  = (const float*)d_in[4];
    const float* rmean = (const float*)d_in[5];
    const float* rvar  = (const float*)d_in[6];
    float* out = (float*)d_out;

    char* ws = (char*)d_ws;
    short*          xTb   = (short*)(ws);
    short*          Wb    = (short*)(ws + 8388608);
    float*          scale = (float*)(ws + 8421376);
    float*          bias  = (float*)(ws + 8421888);
    float4*         pts   = (float4*)(ws + 8422400);
    unsigned short* knn   = (unsigned short*)(ws + 8946688);
    short*          Zb    = (short*)(ws + 9995264);

    // grid scratch overlays Zb (consumed before zgemm writes Zb)
    char* gz = (char*)Zb;
    unsigned*       counts = (unsigned*)(gz);
    unsigned*       fill   = (unsigned*)(gz + 131072);
    unsigned*       starts = (unsigned*)(gz + 262144);
    unsigned*       cellid = (unsigned*)(gz + 393216);
    float4*         psort  = (float4*)(gz + 524288);
    unsigned short* isort  = (unsigned short*)(gz + 1048576);

    transpose_kernel<<<BATCH * 64 * 2, 256, 0, stream>>>(x, xTb);
    small_prep_kernel<<<BATCH * NPTS / 256, 256, 0, stream>>>(
        xyz, W, gamma, beta, rmean, rvar, Wb, scale, bias, pts);
    zero_kernel<<<64, 256, 0, stream>>>((uint4*)gz);   // counts + fill (256 KB)
    hist_kernel<<<BATCH * NPTS / 256, 256, 0, stream>>>(pts, counts, cellid);
    scan_kernel<<<BATCH, 1024, 0, stream>>>(counts, starts);
    scatter_kernel<<<BATCH * NPTS / 256, 256, 0, stream>>>(
        pts, cellid, starts, fill, psort, isort);
    knn_grid_kernel<<<BATCH * NPTS / 16, 256, 0, stream>>>(
        psort, isort, starts, knn);
    zgemm_kernel<<<BATCH * NPTS / 64, 256, 0, stream>>>(xTb, Wb, Zb);
    gmax_kernel<<<BATCH * NPTS / 16, 256, 0, stream>>>(Zb, knn, scale, bias, out);
}